// Round 2
// baseline (1178.770 us; speedup 1.0000x reference)
//
#include <hip/hip_runtime.h>
#include <hip/hip_bf16.h>

#define B_   4
#define S_   2048
#define HID  512
#define H_   8
#define HD   64
#define M_   (B_*S_)   // 8192

// ---------------------------------------------------------------------------
// Kernel 1: QKV projection GEMM (M=8192, K=512, N=512) + fused xPos epilogue.
// gridDim.z = 3 selects Q / K / V. Output layout (b, n, s, d) fp32.
// ---------------------------------------------------------------------------
__global__ __launch_bounds__(256) void qkv_kernel(
    const float* __restrict__ X,
    const float* __restrict__ Wq,
    const float* __restrict__ Wk,
    const float* __restrict__ Wv,
    float* __restrict__ Qf, float* __restrict__ Kf, float* __restrict__ Vf)
{
    __shared__ float As[64][65];
    __shared__ float Bs[64][65];

    const int which = blockIdx.z;
    const float* W   = (which == 0) ? Wq : (which == 1) ? Wk : Wv;
    float*       Out = (which == 0) ? Qf : (which == 1) ? Kf : Vf;

    const int n     = blockIdx.x;        // head (N-tile spans exactly one head)
    const int tileM = blockIdx.y * 64;
    const int tid = threadIdx.x;
    const int tx = tid & 15, ty = tid >> 4;

    float acc[4][4] = {};

    for (int k0 = 0; k0 < HID; k0 += 64) {
        #pragma unroll
        for (int i = 0; i < 4; ++i) {
            int idx = i * 256 + tid;           // 0..1023 float4 slots
            int r = idx >> 4, c = (idx & 15) * 4;
            float4 av = *(const float4*)&X[(size_t)(tileM + r) * HID + (k0 + c)];
            float4 bv = *(const float4*)&W[((size_t)n * HID + (k0 + r)) * HD + c];
            As[r][c] = av.x; As[r][c+1] = av.y; As[r][c+2] = av.z; As[r][c+3] = av.w;
            Bs[r][c] = bv.x; Bs[r][c+1] = bv.y; Bs[r][c+2] = bv.z; Bs[r][c+3] = bv.w;
        }
        __syncthreads();
        #pragma unroll
        for (int kk = 0; kk < 64; ++kk) {
            float a0[4], b0[4];
            #pragma unroll
            for (int a = 0; a < 4; ++a) a0[a] = As[ty * 4 + a][kk];
            #pragma unroll
            for (int b = 0; b < 4; ++b) b0[b] = Bs[kk][tx * 4 + b];
            #pragma unroll
            for (int a = 0; a < 4; ++a)
                #pragma unroll
                for (int b = 0; b < 4; ++b)
                    acc[a][b] += a0[a] * b0[b];
        }
        __syncthreads();
    }

    // epilogue: xPos for Q (scale^+) and K (scale^-), plain for V
    const int d0 = tx * 4;
    #pragma unroll
    for (int a = 0; a < 4; ++a) {
        int m = tileM + ty * 4 + a;
        int bb = m >> 11, s = m & 2047;
        float* dst = Out + (((size_t)bb * H_ + n) * S_ + s) * HD;
        if (which == 2) {
            #pragma unroll
            for (int b = 0; b < 4; ++b) dst[d0 + b] = acc[a][b];
        } else {
            float sgn = (which == 0) ? 1.0f : -1.0f;
            #pragma unroll
            for (int p = 0; p < 2; ++p) {
                int d = d0 + p * 2;
                int k = d >> 1;                       // 0..31
                float sk   = (2.0f * k + 0.4f * HD) / (1.4f * HD);
                float invf = 1.0f / powf(10000.0f, (float)k / 32.0f);
                float ang  = (float)s * invf;
                float sc   = powf(sk, sgn * (float)s / 512.0f);
                float cs = cosf(ang) * sc;
                float sn = sinf(ang) * sc;
                float e = acc[a][p * 2], o = acc[a][p * 2 + 1];
                dst[d]     = e * cs - o * sn;
                dst[d + 1] = o * cs + e * sn;
            }
        }
    }
}

// ---------------------------------------------------------------------------
// Kernel 2: retention. One block per (query-chunk c, b*H+n).
// Block-causal mask allows key chunks 0..c fully; decay = gamma^|i-j|
// (note: within the diagonal chunk j>i IS allowed, matching the reference).
// LDS: Qs[64][65], KtVs[64][65] (K transposed, then reused for V), Ps[64][65].
// ---------------------------------------------------------------------------
__global__ __launch_bounds__(256) void retention_kernel(
    const float* __restrict__ Qf, const float* __restrict__ Kf,
    const float* __restrict__ Vf, float* __restrict__ Yf)
{
    __shared__ float Qs[64][65];
    __shared__ float KtVs[64][65];
    __shared__ float Ps[64][65];

    const int c  = blockIdx.x;       // query chunk 0..31
    const int bn = blockIdx.y;       // b*H + n
    const int n  = bn & 7, bb = bn >> 3;
    const int tid = threadIdx.x;
    const int tx = tid & 15, ty = tid >> 4;

    // gammas: 1 - exp(linspace(log(1/32), log(1/512), 8))
    const float L0   = -3.4657359027997265f;
    const float STEP = -0.3960841031771116f;
    float gamma = 1.0f - expf(L0 + STEP * (float)n);
    float lg = log2f(gamma);         // negative

    const float* Qp = Qf + ((size_t)bn * S_ + c * 64) * HD;
    #pragma unroll
    for (int i = 0; i < 4; ++i) {
        int idx = i * 256 + tid;
        int r = idx >> 4, cc = (idx & 15) * 4;
        float4 v = *(const float4*)&Qp[r * HD + cc];
        Qs[r][cc] = v.x; Qs[r][cc+1] = v.y; Qs[r][cc+2] = v.z; Qs[r][cc+3] = v.w;
    }

    float acc[4][4] = {};

    for (int c2 = 0; c2 <= c; ++c2) {
        const float* Kp = Kf + ((size_t)bn * S_ + c2 * 64) * HD;
        const float* Vp = Vf + ((size_t)bn * S_ + c2 * 64) * HD;

        __syncthreads();  // prev iter done reading Ps/V (also orders Qs store)
        #pragma unroll
        for (int i = 0; i < 4; ++i) {
            int idx = i * 256 + tid;
            int r = idx >> 4, cc = (idx & 15) * 4;
            float4 v = *(const float4*)&Kp[r * HD + cc];
            KtVs[cc][r] = v.x; KtVs[cc+1][r] = v.y;   // K transposed: [kk][jj]
            KtVs[cc+2][r] = v.z; KtVs[cc+3][r] = v.w;
        }
        __syncthreads();

        // P = Q K^T (this chunk pair)
        float p[4][4] = {};
        #pragma unroll
        for (int kk = 0; kk < 64; ++kk) {
            float q0[4], k0v[4];
            #pragma unroll
            for (int a = 0; a < 4; ++a) q0[a] = Qs[ty * 4 + a][kk];
            #pragma unroll
            for (int b = 0; b < 4; ++b) k0v[b] = KtVs[kk][tx * 4 + b];
            #pragma unroll
            for (int a = 0; a < 4; ++a)
                #pragma unroll
                for (int b = 0; b < 4; ++b)
                    p[a][b] += q0[a] * k0v[b];
        }

        __syncthreads();  // all threads done reading K before V overwrites it
        #pragma unroll
        for (int i = 0; i < 4; ++i) {
            int idx = i * 256 + tid;
            int r = idx >> 4, cc = (idx & 15) * 4;
            float4 v = *(const float4*)&Vp[r * HD + cc];
            KtVs[r][cc] = v.x; KtVs[r][cc+1] = v.y;   // V natural: [jj][d]
            KtVs[r][cc+2] = v.z; KtVs[r][cc+3] = v.w;
        }
        #pragma unroll
        for (int a = 0; a < 4; ++a) {
            int ii = c * 64 + ty * 4 + a;
            #pragma unroll
            for (int b = 0; b < 4; ++b) {
                int jj = c2 * 64 + tx * 4 + b;
                float dec = exp2f(lg * fabsf((float)(ii - jj)));
                Ps[ty * 4 + a][tx * 4 + b] = p[a][b] * dec;
            }
        }
        __syncthreads();

        // acc += Ps @ V
        #pragma unroll
        for (int kk = 0; kk < 64; ++kk) {
            float pv[4], vv[4];
            #pragma unroll
            for (int a = 0; a < 4; ++a) pv[a] = Ps[ty * 4 + a][kk];
            #pragma unroll
            for (int b = 0; b < 4; ++b) vv[b] = KtVs[kk][tx * 4 + b];
            #pragma unroll
            for (int a = 0; a < 4; ++a)
                #pragma unroll
                for (int b = 0; b < 4; ++b)
                    acc[a][b] += pv[a] * vv[b];
        }
    }

    // write Y in (b, s, n, d) layout
    #pragma unroll
    for (int a = 0; a < 4; ++a) {
        int s = c * 64 + ty * 4 + a;
        float* dst = Yf + (((size_t)bb * S_ + s) * H_ + n) * HD + tx * 4;
        #pragma unroll
        for (int b = 0; b < 4; ++b) dst[b] = acc[a][b];
    }
}

// ---------------------------------------------------------------------------
// Kernel 3: gate GEMM  G = silu(X @ W_G), row-major W_G (512x512), fp32 out.
// ---------------------------------------------------------------------------
__global__ __launch_bounds__(256) void gate_kernel(
    const float* __restrict__ X,
    const float* __restrict__ Wg,
    float* __restrict__ G)
{
    __shared__ float As[64][65];
    __shared__ float Bs[64][65];

    const int tileN = blockIdx.x * 64;
    const int tileM = blockIdx.y * 64;
    const int tid = threadIdx.x;
    const int tx = tid & 15, ty = tid >> 4;

    float acc[4][4] = {};
    for (int k0 = 0; k0 < HID; k0 += 64) {
        #pragma unroll
        for (int i = 0; i < 4; ++i) {
            int idx = i * 256 + tid;
            int r = idx >> 4, c = (idx & 15) * 4;
            float4 av = *(const float4*)&X[(size_t)(tileM + r) * HID + (k0 + c)];
            float4 bv = *(const float4*)&Wg[(size_t)(k0 + r) * HID + (tileN + c)];
            As[r][c] = av.x; As[r][c+1] = av.y; As[r][c+2] = av.z; As[r][c+3] = av.w;
            Bs[r][c] = bv.x; Bs[r][c+1] = bv.y; Bs[r][c+2] = bv.z; Bs[r][c+3] = bv.w;
        }
        __syncthreads();
        #pragma unroll
        for (int kk = 0; kk < 64; ++kk) {
            float a0[4], b0[4];
            #pragma unroll
            for (int a = 0; a < 4; ++a) a0[a] = As[ty * 4 + a][kk];
            #pragma unroll
            for (int b = 0; b < 4; ++b) b0[b] = Bs[kk][tx * 4 + b];
            #pragma unroll
            for (int a = 0; a < 4; ++a)
                #pragma unroll
                for (int b = 0; b < 4; ++b)
                    acc[a][b] += a0[a] * b0[b];
        }
        __syncthreads();
    }
    #pragma unroll
    for (int a = 0; a < 4; ++a) {
        int m = tileM + ty * 4 + a;
        #pragma unroll
        for (int b = 0; b < 4; ++b) {
            float g = acc[a][b];
            G[(size_t)m * HID + tileN + tx * 4 + b] = g / (1.0f + expf(-g));
        }
    }
}

// ---------------------------------------------------------------------------
// Kernel 4: per-head groupnorm over hd=64, affine, multiply by gate. One wave
// per (b,s,head). Y layout (b,s,n,d). Z = gate * Yn, fp32.
// ---------------------------------------------------------------------------
__global__ __launch_bounds__(64) void gn_kernel(
    const float* __restrict__ Yf, const float* __restrict__ G,
    const float* __restrict__ gw, const float* __restrict__ gb,
    float* __restrict__ Z)
{
    const int g = blockIdx.x;        // (b*S+s)*H + n
    const int t = threadIdx.x;       // d
    const int bs = g >> 3, n = g & 7;

    float y = Yf[(size_t)g * 64 + t];
    float sum = y, sq = y * y;
    #pragma unroll
    for (int off = 32; off; off >>= 1) {
        sum += __shfl_xor(sum, off);
        sq  += __shfl_xor(sq, off);
    }
    float mu  = sum * (1.0f / 64.0f);
    float var = sq * (1.0f / 64.0f) - mu * mu;
    float rstd = rsqrtf(var + 1e-5f);

    int j = n * 64 + t;
    float yn = (y - mu) * rstd * gw[j] + gb[j];
    Z[(size_t)bs * HID + j] = G[(size_t)bs * HID + j] * yn;
}

// ---------------------------------------------------------------------------
// Kernel 5: output GEMM  out = Z @ W_O  (fp32 in/out).
// ---------------------------------------------------------------------------
__global__ __launch_bounds__(256) void out_kernel(
    const float* __restrict__ Z,
    const float* __restrict__ Wo,
    float* __restrict__ out)
{
    __shared__ float As[64][65];
    __shared__ float Bs[64][65];

    const int tileN = blockIdx.x * 64;
    const int tileM = blockIdx.y * 64;
    const int tid = threadIdx.x;
    const int tx = tid & 15, ty = tid >> 4;

    float acc[4][4] = {};
    for (int k0 = 0; k0 < HID; k0 += 64) {
        #pragma unroll
        for (int i = 0; i < 4; ++i) {
            int idx = i * 256 + tid;
            int r = idx >> 4, c = (idx & 15) * 4;
            float4 av = *(const float4*)&Z[(size_t)(tileM + r) * HID + (k0 + c)];
            float4 bv = *(const float4*)&Wo[(size_t)(k0 + r) * HID + (tileN + c)];
            As[r][c] = av.x; As[r][c+1] = av.y; As[r][c+2] = av.z; As[r][c+3] = av.w;
            Bs[r][c] = bv.x; Bs[r][c+1] = bv.y; Bs[r][c+2] = bv.z; Bs[r][c+3] = bv.w;
        }
        __syncthreads();
        #pragma unroll
        for (int kk = 0; kk < 64; ++kk) {
            float a0[4], b0[4];
            #pragma unroll
            for (int a = 0; a < 4; ++a) a0[a] = As[ty * 4 + a][kk];
            #pragma unroll
            for (int b = 0; b < 4; ++b) b0[b] = Bs[kk][tx * 4 + b];
            #pragma unroll
            for (int a = 0; a < 4; ++a)
                #pragma unroll
                for (int b = 0; b < 4; ++b)
                    acc[a][b] += a0[a] * b0[b];
        }
        __syncthreads();
    }
    #pragma unroll
    for (int a = 0; a < 4; ++a) {
        int m = tileM + ty * 4 + a;
        #pragma unroll
        for (int b = 0; b < 4; ++b)
            out[(size_t)m * HID + tileN + tx * 4 + b] = acc[a][b];
    }
}

// ---------------------------------------------------------------------------
extern "C" void kernel_launch(void* const* d_in, const int* in_sizes, int n_in,
                              void* d_out, int out_size, void* d_ws, size_t ws_size,
                              hipStream_t stream)
{
    const float* X  = (const float*)d_in[0];
    const float* Wq = (const float*)d_in[1];
    const float* Wk = (const float*)d_in[2];
    const float* Wv = (const float*)d_in[3];
    const float* Wg = (const float*)d_in[4];
    const float* Wo = (const float*)d_in[5];
    const float* gw = (const float*)d_in[6];
    const float* gb = (const float*)d_in[7];
    // d_in[8] = chunk_size (int scalar) — fixed at 64, baked into the kernels.

    const size_t NTOK = (size_t)B_ * H_ * S_ * HD;   // 4,194,304 floats
    float* Qf = (float*)d_ws;
    float* Kf = Qf + NTOK;
    float* Vf = Kf + NTOK;
    float* Yf = Vf + NTOK;
    float* Gf = Kf;   // reused after retention (stream-ordered)
    float* Zf = Qf;   // reused after retention

    qkv_kernel<<<dim3(8, 128, 3), dim3(256), 0, stream>>>(X, Wq, Wk, Wv, Qf, Kf, Vf);
    retention_kernel<<<dim3(32, 32), dim3(256), 0, stream>>>(Qf, Kf, Vf, Yf);
    gate_kernel<<<dim3(8, 128), dim3(256), 0, stream>>>(X, Wg, Gf);
    gn_kernel<<<dim3(B_ * S_ * H_), dim3(64), 0, stream>>>(Yf, Gf, gw, gb, Zf);
    out_kernel<<<dim3(8, 128), dim3(256), 0, stream>>>(Zf, Wo, (float*)d_out);
}

// Round 3
// 259.878 us; speedup vs baseline: 4.5359x; 4.5359x over previous
//
#include <hip/hip_runtime.h>

#define B_   4
#define S_   2048
#define HID  512
#define H_   8
#define HD   64

typedef __attribute__((ext_vector_type(8))) short bf16x8;
typedef __attribute__((ext_vector_type(4))) float f32x4;

#define MFMA16(a, b, c) __builtin_amdgcn_mfma_f32_16x16x32_bf16(a, b, c, 0, 0, 0)

__device__ __forceinline__ void async16(const void* g, void* l) {
    __builtin_amdgcn_global_load_lds(
        (const __attribute__((address_space(1))) void*)g,
        (__attribute__((address_space(3))) void*)l, 16, 0, 0);
}

__device__ __forceinline__ unsigned short f2bf(float x) {
    unsigned u = __float_as_uint(x);
    return (unsigned short)((u + 0x7fffu + ((u >> 16) & 1u)) >> 16);
}

// ---------------------------------------------------------------------------
// Convert X fp32 -> bf16 (row-major [8192][512]).
// ---------------------------------------------------------------------------
__global__ __launch_bounds__(256) void convert_x(const float* __restrict__ X,
                                                 short* __restrict__ Xb)
{
    size_t i = ((size_t)blockIdx.x * 256 + threadIdx.x) * 8;
    float4 a = *(const float4*)&X[i];
    float4 b = *(const float4*)&X[i + 4];
    union { int4 v; unsigned short s[8]; } u;
    u.s[0] = f2bf(a.x); u.s[1] = f2bf(a.y); u.s[2] = f2bf(a.z); u.s[3] = f2bf(a.w);
    u.s[4] = f2bf(b.x); u.s[5] = f2bf(b.y); u.s[6] = f2bf(b.z); u.s[7] = f2bf(b.w);
    *(int4*)&Xb[i] = u.v;
}

// ---------------------------------------------------------------------------
// Transpose-convert all 5 weights to bf16 WT[n][k] (ld = 512).
// Blocks 0..191: QKV (which,h,ktile). Blocks 192..319: G/O (which,ntile,ktile).
// ---------------------------------------------------------------------------
__global__ __launch_bounds__(256) void transpose_w(
    const float* __restrict__ Wq, const float* __restrict__ Wk,
    const float* __restrict__ Wv, const float* __restrict__ Wg,
    const float* __restrict__ Wo,
    short* __restrict__ WqT, short* __restrict__ WkT, short* __restrict__ WvT,
    short* __restrict__ WgT, short* __restrict__ WoT)
{
    __shared__ float T[64][65];
    const int bid = blockIdx.x, t = threadIdx.x;

    const float* ip; short* op; int ild;
    if (bid < 192) {
        int which = bid >> 6, rem = bid & 63, h = rem >> 3, kt = rem & 7;
        const float* src = which == 0 ? Wq : which == 1 ? Wk : Wv;
        short* dst       = which == 0 ? WqT : which == 1 ? WkT : WvT;
        ip = src + ((size_t)h * 512 + kt * 64) * 64;   // rows k-local, cols d
        ild = 64;
        op = dst + (size_t)(h * 64) * 512 + kt * 64;   // row n=h*64+d, col k
    } else {
        int rem = bid - 192, which = rem >> 6, r3 = rem & 63, nt = r3 >> 3, kt = r3 & 7;
        const float* src = which ? Wo : Wg;
        short* dst       = which ? WoT : WgT;
        ip = src + (size_t)(kt * 64) * 512 + nt * 64;  // rows k-local, cols n-local
        ild = 512;
        op = dst + (size_t)(nt * 64) * 512 + kt * 64;
    }

    {
        int r = t >> 2, c0 = (t & 3) * 16;
        #pragma unroll
        for (int e = 0; e < 4; ++e) {
            float4 f = *(const float4*)&ip[(size_t)r * ild + c0 + e * 4];
            T[r][c0 + e*4 + 0] = f.x; T[r][c0 + e*4 + 1] = f.y;
            T[r][c0 + e*4 + 2] = f.z; T[r][c0 + e*4 + 3] = f.w;
        }
    }
    __syncthreads();
    {
        int cc = t >> 2, r0 = (t & 3) * 16;
        short* orow = op + (size_t)cc * 512;
        #pragma unroll
        for (int ii = 0; ii < 8; ++ii) {
            int lo = f2bf(T[r0 + 2*ii][cc]);
            int hi = f2bf(T[r0 + 2*ii + 1][cc]);
            *(int*)(orow + r0 + 2*ii) = (lo & 0xffff) | (hi << 16);
        }
    }
}

// ---------------------------------------------------------------------------
// m97-style 128x128 bf16 MFMA GEMM core. A[m][k] ld=512, Bt[n][k] ld=512.
// 256 threads = 4 waves in 2x2; each wave: 4x4 tiles of 16x16 (mfma 16x16x32).
// ---------------------------------------------------------------------------
__device__ __forceinline__ void gemm_core(const short* __restrict__ Ag,
                                          const short* __restrict__ Bg,
                                          short* As, short* Bs,
                                          f32x4 (&acc)[4][4])
{
    const int tid = threadIdx.x;
    const int L = tid & 63, quad = L >> 4, l16 = L & 15;
    const int w = tid >> 6;
    const int wrow = (w >> 1) * 64, wcol = (w & 1) * 64;

    const short* ga = Ag + (size_t)(tid >> 2) * 512 + (tid & 3) * 8;
    const short* gb = Bg + (size_t)(tid >> 2) * 512 + (tid & 3) * 8;
    short* la0 = As + tid * 8;
    short* la1 = As + 2048 + tid * 8;
    short* lb0 = Bs + tid * 8;
    short* lb1 = Bs + 2048 + tid * 8;

    for (int k0 = 0; k0 < 512; k0 += 32) {
        async16(ga + k0,             la0);
        async16(ga + k0 + 64 * 512,  la1);
        async16(gb + k0,             lb0);
        async16(gb + k0 + 64 * 512,  lb1);
        __syncthreads();

        bf16x8 af[4], bfr[4];
        #pragma unroll
        for (int a = 0; a < 4; ++a)
            af[a] = *(const bf16x8*)&As[(wrow + a*16 + l16) * 32 + quad * 8];
        #pragma unroll
        for (int b = 0; b < 4; ++b)
            bfr[b] = *(const bf16x8*)&Bs[(wcol + b*16 + l16) * 32 + quad * 8];
        #pragma unroll
        for (int a = 0; a < 4; ++a)
            #pragma unroll
            for (int b = 0; b < 4; ++b)
                acc[a][b] = MFMA16(af[a], bfr[b], acc[a][b]);
        __syncthreads();
    }
}

// ---------------------------------------------------------------------------
// QKV projection: grid (4, 64, 3). Epilogue: xPos for Q/K, plain for V.
// Outputs bf16 (b, n, s, d).
// ---------------------------------------------------------------------------
__global__ __launch_bounds__(256) void qkv_gemm(
    const short* __restrict__ Xb,
    const short* __restrict__ WqT, const short* __restrict__ WkT,
    const short* __restrict__ WvT,
    short* __restrict__ Qb, short* __restrict__ Kb, short* __restrict__ Vb)
{
    __shared__ short As[4096], Bs[4096];
    const int z = blockIdx.z;
    const short* W = z == 0 ? WqT : z == 1 ? WkT : WvT;

    f32x4 acc[4][4];
    #pragma unroll
    for (int a = 0; a < 4; ++a)
        #pragma unroll
        for (int b = 0; b < 4; ++b) acc[a][b] = (f32x4){0.f, 0.f, 0.f, 0.f};

    gemm_core(Xb + (size_t)blockIdx.y * 128 * 512,
              W  + (size_t)blockIdx.x * 128 * 512, As, Bs, acc);

    const int tid = threadIdx.x, L = tid & 63, quad = L >> 4, l16 = L & 15;
    const int w = tid >> 6, wrow = (w >> 1) * 64, wcol = (w & 1) * 64;
    short* QK = (z == 0) ? Qb : Kb;
    const float sgn = (z == 0) ? 1.0f : -1.0f;

    #pragma unroll
    for (int b = 0; b < 4; ++b) {
        int ncol = blockIdx.x * 128 + wcol + b * 16 + l16;
        int h = ncol >> 6, d = ncol & 63;
        float invf = 0.f, lsk = 0.f;
        if (z < 2) {
            int k = d >> 1;
            invf = exp2f(-0.41524101186092035f * (float)k);  // 10000^(-k/32)
            lsk  = log2f(((float)(2 * k) + 25.6f) / 89.6f) * (1.0f / 512.0f);
        }
        #pragma unroll
        for (int a = 0; a < 4; ++a) {
            #pragma unroll
            for (int r = 0; r < 4; ++r) {
                int m = blockIdx.y * 128 + wrow + a * 16 + quad * 4 + r;
                int bb = m >> 11, s = m & 2047;
                float v = acc[a][b][r];
                size_t o = (((size_t)bb * 8 + h) * 2048 + s) * 64 + d;
                if (z == 2) {
                    Vb[o] = (short)f2bf(v);
                } else {
                    float sc  = exp2f(sgn * (float)s * lsk);
                    float ang = (float)s * invf;
                    float cs = cosf(ang) * sc, sn = sinf(ang) * sc;
                    float part = __shfl_xor(v, 1);
                    float res = (d & 1) ? (v * cs + part * sn)
                                        : (v * cs - part * sn);
                    QK[o] = (short)f2bf(res);
                }
            }
        }
    }
}

// ---------------------------------------------------------------------------
// Gate GEMM: Gf = silu(X @ W_G), fp32 [8192][512]. grid (4, 64).
// ---------------------------------------------------------------------------
__global__ __launch_bounds__(256) void gate_gemm(
    const short* __restrict__ Xb, const short* __restrict__ WgT,
    float* __restrict__ Gf)
{
    __shared__ short As[4096], Bs[4096];
    f32x4 acc[4][4];
    #pragma unroll
    for (int a = 0; a < 4; ++a)
        #pragma unroll
        for (int b = 0; b < 4; ++b) acc[a][b] = (f32x4){0.f, 0.f, 0.f, 0.f};

    gemm_core(Xb + (size_t)blockIdx.y * 128 * 512,
              WgT + (size_t)blockIdx.x * 128 * 512, As, Bs, acc);

    const int tid = threadIdx.x, L = tid & 63, quad = L >> 4, l16 = L & 15;
    const int w = tid >> 6, wrow = (w >> 1) * 64, wcol = (w & 1) * 64;
    #pragma unroll
    for (int b = 0; b < 4; ++b) {
        int ncol = blockIdx.x * 128 + wcol + b * 16 + l16;
        #pragma unroll
        for (int a = 0; a < 4; ++a)
            #pragma unroll
            for (int r = 0; r < 4; ++r) {
                int m = blockIdx.y * 128 + wrow + a * 16 + quad * 4 + r;
                float g = acc[a][b][r];
                Gf[(size_t)m * 512 + ncol] = g / (1.0f + __expf(-g));
            }
    }
}

// ---------------------------------------------------------------------------
// Output GEMM: out = Z @ W_O, fp32 out. grid (4, 64).
// ---------------------------------------------------------------------------
__global__ __launch_bounds__(256) void out_gemm(
    const short* __restrict__ Zb, const short* __restrict__ WoT,
    float* __restrict__ Of)
{
    __shared__ short As[4096], Bs[4096];
    f32x4 acc[4][4];
    #pragma unroll
    for (int a = 0; a < 4; ++a)
        #pragma unroll
        for (int b = 0; b < 4; ++b) acc[a][b] = (f32x4){0.f, 0.f, 0.f, 0.f};

    gemm_core(Zb + (size_t)blockIdx.y * 128 * 512,
              WoT + (size_t)blockIdx.x * 128 * 512, As, Bs, acc);

    const int tid = threadIdx.x, L = tid & 63, quad = L >> 4, l16 = L & 15;
    const int w = tid >> 6, wrow = (w >> 1) * 64, wcol = (w & 1) * 64;
    #pragma unroll
    for (int b = 0; b < 4; ++b) {
        int ncol = blockIdx.x * 128 + wcol + b * 16 + l16;
        #pragma unroll
        for (int a = 0; a < 4; ++a)
            #pragma unroll
            for (int r = 0; r < 4; ++r) {
                int m = blockIdx.y * 128 + wrow + a * 16 + quad * 4 + r;
                Of[(size_t)m * 512 + ncol] = acc[a][b][r];
            }
    }
}

// ---------------------------------------------------------------------------
// Retention (MFMA). grid (16, 32): block x handles query chunks {x, 31-x}
// (uniform 33 chunk-pairs). 256 threads; wave w owns S/O rows 16w..16w+15.
// QK^T: A=Q rows, B=K rows. PV: P via per-wave LDS (A-layout), B=V^T (LDS
// transpose at stage time). Decay = gamma^|i-j| via precomputed local table
// x one exp2f per key chunk. Y out fp32 (b, s, h, d).
// ---------------------------------------------------------------------------
__global__ __launch_bounds__(256) void retention_kernel(
    const short* __restrict__ Qb, const short* __restrict__ Kb,
    const short* __restrict__ Vb, float* __restrict__ Yf)
{
    __shared__ short Qs[4096];       // 2 regions [64][32]
    __shared__ short Ks[4096];       // 2 regions [64][32]
    __shared__ short Vt[64 * 72];    // [d][j] padded
    __shared__ short Pw[4][16 * 72]; // per-wave P block [16][64+8]

    const int tid = threadIdx.x, L = tid & 63, quad = L >> 4, l16 = L & 15;
    const int w = tid >> 6;
    const int bn = blockIdx.y, hh = bn & 7, bb = bn >> 3;

    const float L0 = -3.4657359027997265f, STEP = -0.3960841031771116f;
    float gamma = 1.0f - expf(L0 + STEP * (float)hh);
    float lg = log2f(gamma);                    // negative

    float Dloc[4][4], Dabs[4][4];
    #pragma unroll
    for (int b = 0; b < 4; ++b)
        #pragma unroll
        for (int r = 0; r < 4; ++r) {
            int dlt = (w * 16 + quad * 4 + r) - (b * 16 + l16);
            Dloc[b][r] = exp2f(lg * (float)dlt);
            Dabs[b][r] = exp2f(lg * fabsf((float)dlt));
        }

    const short* Qbase = Qb + (size_t)bn * 2048 * 64;
    const short* Kbase = Kb + (size_t)bn * 2048 * 64;
    const short* Vbase = Vb + (size_t)bn * 2048 * 64;

    for (int phase = 0; phase < 2; ++phase) {
        const int c = phase ? (31 - blockIdx.x) : blockIdx.x;
        __syncthreads();   // all waves done with previous phase's LDS reads
        {
            const short* g = Qbase + (size_t)(c * 64 + w * 16 + (L >> 2)) * 64 + (L & 3) * 8;
            async16(g,      Qs + w * 512 + L * 8);
            async16(g + 32, Qs + 2048 + w * 512 + L * 8);
        }
        f32x4 acc[4];
        #pragma unroll
        for (int b2 = 0; b2 < 4; ++b2) acc[b2] = (f32x4){0.f, 0.f, 0.f, 0.f};

        for (int c2 = 0; c2 <= c; ++c2) {
            __syncthreads();   // prior iteration's Ks/Vt reads complete
            {
                const short* g = Kbase + (size_t)(c2 * 64 + w * 16 + (L >> 2)) * 64 + (L & 3) * 8;
                async16(g,      Ks + w * 512 + L * 8);
                async16(g + 32, Ks + 2048 + w * 512 + L * 8);
            }
            {   // V transpose staging: thread (w,L): row j=L, d = 16w..16w+15
                const short* g = Vbase + (size_t)(c2 * 64 + L) * 64 + w * 16;
                int4 v0 = *(const int4*)g;
                int4 v1 = *(const int4*)(g + 8);
                short* vt = Vt + L;
                #pragma unroll
                for (int q = 0; q < 4; ++q) {
                    int u = ((const int*)&v0)[q];
                    vt[(w * 16 + 2 * q) * 72]     = (short)u;
                    vt[(w * 16 + 2 * q + 1) * 72] = (short)(u >> 16);
                }
                #pragma unroll
                for (int q = 0; q < 4; ++q) {
                    int u = ((const int*)&v1)[q];
                    vt[(w * 16 + 8 + 2 * q) * 72] = (short)u;
                    vt[(w * 16 + 9 + 2 * q) * 72] = (short)(u >> 16);
                }
            }
            __syncthreads();   // Ks DMA drained + Vt writes visible

            // ---- QK^T with decay -> Pw (bf16, A-layout rows) ----
            bf16x8 aQ0 = *(const bf16x8*)&Qs[(w * 16 + l16) * 32 + quad * 8];
            bf16x8 aQ1 = *(const bf16x8*)&Qs[2048 + (w * 16 + l16) * 32 + quad * 8];
            float cf = exp2f(lg * (float)(64 * (c - c2)));
            const bool diag = (c2 == c);
            #pragma unroll
            for (int b = 0; b < 4; ++b) {
                bf16x8 k0 = *(const bf16x8*)&Ks[(b * 16 + l16) * 32 + quad * 8];
                bf16x8 k1 = *(const bf16x8*)&Ks[2048 + (b * 16 + l16) * 32 + quad * 8];
                f32x4 S = (f32x4){0.f, 0.f, 0.f, 0.f};
                S = MFMA16(aQ0, k0, S);
                S = MFMA16(aQ1, k1, S);
                #pragma unroll
                for (int r = 0; r < 4; ++r) {
                    float dec = diag ? Dabs[b][r] : Dloc[b][r] * cf;
                    Pw[w][(quad * 4 + r) * 72 + b * 16 + l16] = (short)f2bf(S[r] * dec);
                }
            }

            // ---- PV ----
            bf16x8 aP0 = *(const bf16x8*)&Pw[w][l16 * 72 + quad * 8];
            bf16x8 aP1 = *(const bf16x8*)&Pw[w][l16 * 72 + 32 + quad * 8];
            #pragma unroll
            for (int b2 = 0; b2 < 4; ++b2) {
                bf16x8 v0f = *(const bf16x8*)&Vt[(b2 * 16 + l16) * 72 + quad * 8];
                bf16x8 v1f = *(const bf16x8*)&Vt[(b2 * 16 + l16) * 72 + 32 + quad * 8];
                acc[b2] = MFMA16(aP0, v0f, acc[b2]);
                acc[b2] = MFMA16(aP1, v1f, acc[b2]);
            }
        }

        // epilogue: Yf[((bb*2048 + c*64 + i)*8 + hh)*64 + d]
        #pragma unroll
        for (int b2 = 0; b2 < 4; ++b2)
            #pragma unroll
            for (int r = 0; r < 4; ++r) {
                int i = w * 16 + quad * 4 + r;
                int d = b2 * 16 + l16;
                Yf[(((size_t)bb * 2048 + c * 64 + i) * 8 + hh) * 64 + d] = acc[b2][r];
            }
    }
}

// ---------------------------------------------------------------------------
// GroupNorm(hd=64) + affine + gate multiply. 4 waves/block, wave per (m,h).
// Zb bf16 [8192][512].
// ---------------------------------------------------------------------------
__global__ __launch_bounds__(256) void gn_kernel(
    const float* __restrict__ Yf, const float* __restrict__ Gf,
    const float* __restrict__ gw, const float* __restrict__ gb,
    short* __restrict__ Zb)
{
    const int t = threadIdx.x, w = t >> 6, L = t & 63;
    const int unit = blockIdx.x * 4 + w;     // m*8 + h
    const size_t idx = (size_t)unit * 64 + L;

    float y = Yf[idx];
    float sum = y, sq = y * y;
    #pragma unroll
    for (int off = 32; off; off >>= 1) {
        sum += __shfl_xor(sum, off);
        sq  += __shfl_xor(sq, off);
    }
    float mu  = sum * (1.0f / 64.0f);
    float var = sq * (1.0f / 64.0f) - mu * mu;
    float rstd = rsqrtf(var + 1e-5f);

    int j = (unit & 7) * 64 + L;
    float yn = (y - mu) * rstd * gw[j] + gb[j];
    Zb[idx] = (short)f2bf(Gf[idx] * yn);
}

// ---------------------------------------------------------------------------
extern "C" void kernel_launch(void* const* d_in, const int* in_sizes, int n_in,
                              void* d_out, int out_size, void* d_ws, size_t ws_size,
                              hipStream_t stream)
{
    const float* X  = (const float*)d_in[0];
    const float* Wq = (const float*)d_in[1];
    const float* Wk = (const float*)d_in[2];
    const float* Wv = (const float*)d_in[3];
    const float* Wg = (const float*)d_in[4];
    const float* Wo = (const float*)d_in[5];
    const float* gw = (const float*)d_in[6];
    const float* gb = (const float*)d_in[7];

    char* ws = (char*)d_ws;
    short* Xb  = (short*)ws;                          // 8,388,608 B
    short* WqT = (short*)(ws + 8388608);              // 512 KB each
    short* WkT = WqT + 262144;
    short* WvT = WkT + 262144;
    short* WgT = WvT + 262144;
    short* WoT = WgT + 262144;
    short* Qb  = (short*)(ws + 11010048);             // 8,388,608 B each
    short* Kb  = Qb + 4194304;
    short* Vb  = Kb + 4194304;
    float* Yf  = (float*)(ws + 36175872);             // 16,777,216 B
    float* Gf  = (float*)Qb;                          // overlay Qb+Kb (post-retention)
    short* Zb  = Vb;                                  // overlay Vb   (post-retention)

    convert_x<<<2048, 256, 0, stream>>>(X, Xb);
    transpose_w<<<320, 256, 0, stream>>>(Wq, Wk, Wv, Wg, Wo, WqT, WkT, WvT, WgT, WoT);
    qkv_gemm<<<dim3(4, 64, 3), 256, 0, stream>>>(Xb, WqT, WkT, WvT, Qb, Kb, Vb);
    retention_kernel<<<dim3(16, 32), 256, 0, stream>>>(Qb, Kb, Vb, Yf);
    gate_gemm<<<dim3(4, 64), 256, 0, stream>>>(Xb, WgT, Gf);
    gn_kernel<<<16384, 256, 0, stream>>>(Yf, Gf, gw, gb, Zb);
    out_gemm<<<dim3(4, 64), 256, 0, stream>>>(Zb, WoT, (float*)d_out);
}